// Round 1
// baseline (384.021 us; speedup 1.0000x reference)
//
#include <hip/hip_runtime.h>

#define HH 16
#define DKK 64
#define SS 2048
#define BB 2
#define DD 1024

typedef __attribute__((ext_vector_type(4))) float f32x4;
typedef __attribute__((ext_vector_type(8))) short bf16x8;
typedef __attribute__((ext_vector_type(4))) short s16x4;

__device__ __forceinline__ short bf16b(float f) {
    union { float f; unsigned u; } x; x.f = f;
    unsigned r = (x.u + 0x7fffu + ((x.u >> 16) & 1u)) >> 16;
    return (short)r;
}

__device__ __forceinline__ f32x4 mfma16(bf16x8 a, bf16x8 b, f32x4 c) {
    return __builtin_amdgcn_mfma_f32_16x16x32_bf16(a, b, c, 0, 0, 0);
}

// ---------------- fp32 -> bf16 cast (contiguous) ----------------
__global__ __launch_bounds__(256) void cvt_bf16(const float* __restrict__ x,
                                                short* __restrict__ y, int n) {
    int i = (blockIdx.x * 256 + threadIdx.x) * 4;
    if (i >= n) return;
    f32x4 v = *(const f32x4*)(x + i);
    s16x4 o;
    o.x = bf16b(v.x); o.y = bf16b(v.y); o.z = bf16b(v.z); o.w = bf16b(v.w);
    *(s16x4*)(y + i) = o;
}

// ---------------- weight transpose+cast: W[K][N] fp32 -> Wt[N][K] bf16 ----------------
__global__ __launch_bounds__(256) void transpose_w(
    const float* __restrict__ W0, const float* __restrict__ W1,
    const float* __restrict__ W2, const float* __restrict__ W3,
    short* __restrict__ T0, short* __restrict__ T1,
    short* __restrict__ T2, short* __restrict__ T3) {
    const float* W; short* T;
    switch (blockIdx.z) {
        case 0: W = W0; T = T0; break;
        case 1: W = W1; T = T1; break;
        case 2: W = W2; T = T2; break;
        default: W = W3; T = T3; break;
    }
    __shared__ short tile[32][33];
    int n0 = blockIdx.x * 32, k0 = blockIdx.y * 32;
    int tx = threadIdx.x & 31;
    int ty = (threadIdx.x >> 5) * 4; // 8 groups of 4 rows
#pragma unroll
    for (int i = 0; i < 4; i++)
        tile[ty + i][tx] = bf16b(W[(k0 + ty + i) * DD + n0 + tx]);
    __syncthreads();
#pragma unroll
    for (int i = 0; i < 4; i++)
        T[(n0 + ty + i) * DD + k0 + tx] = tile[tx][ty + i];
}

// ---------------- bias table: tab[h][delta+2047], delta = k - q ----------------
__global__ __launch_bounds__(256) void build_bias(const float* __restrict__ rb,
                                                  float* __restrict__ tab) {
    int idx = blockIdx.x * 256 + threadIdx.x;
    if (idx >= HH * 4095) return;
    int h = idx / 4095, d = idx % 4095;
    int rel = d - 2047; // k - q
    int bucket = (rel > 0) ? 16 : 0;
    unsigned r = (rel < 0) ? (unsigned)(-rel) : (unsigned)rel;
    int add;
    if (r < 8) add = (int)r;
    else {
        int e = 31 - __clz(r);
        unsigned long long r2 = (unsigned long long)r * (unsigned long long)r;
        int f = 2 * e + ((r2 >= (2ull << (2 * e))) ? 1 : 0); // floor(2*log2 r)
        add = 8 + (f - 6);
        if (add > 15) add = 15;
    }
    bucket += add;
    tab[h * 4095 + d] = rb[bucket * HH + h];
}

// ---------------- 128x128 tile bf16 GEMM: C = A[M][K] * Bt[N][K]^T ----------------
// EPI 0: z picks {Wq,Wk,Wv}; writes Q/K as [B][H][S][DK] bf16, V transposed [B][H][DK][S]
// EPI 1: writes fp32 [M][N] to Cout
template <int EPI>
__global__ __launch_bounds__(256) void gemm_bt(
    const short* __restrict__ A,
    const short* __restrict__ Bq, const short* __restrict__ Bk, const short* __restrict__ Bv,
    short* __restrict__ Cq, short* __restrict__ Ck, short* __restrict__ Cvt,
    float* __restrict__ Cout) {
    const int K = 1024, N = 1024;
    __shared__ short As[128 * 32];
    __shared__ short Bs[128 * 32];
    int tid = threadIdx.x;
    int wave = tid >> 6, lane = tid & 63;
    int quad = lane >> 4, l16 = lane & 15;
    int m0 = blockIdx.y * 128, n0 = blockIdx.x * 128;
    const short* Bt = Bq;
    if (EPI == 0) { if (blockIdx.z == 1) Bt = Bk; else if (blockIdx.z == 2) Bt = Bv; }

    int wm = (wave & 1) * 64, wn = (wave >> 1) * 64;
    int r0 = tid >> 2, c0 = (tid & 3) * 8;
    int r1 = r0 + 64;

    f32x4 acc[4][4];
#pragma unroll
    for (int i = 0; i < 4; i++)
#pragma unroll
        for (int j = 0; j < 4; j++) acc[i][j] = (f32x4){0.f, 0.f, 0.f, 0.f};

    for (int k0 = 0; k0 < K; k0 += 32) {
        bf16x8 a0 = *(const bf16x8*)(A + (size_t)(m0 + r0) * K + k0 + c0);
        bf16x8 a1 = *(const bf16x8*)(A + (size_t)(m0 + r1) * K + k0 + c0);
        bf16x8 b0 = *(const bf16x8*)(Bt + (size_t)(n0 + r0) * K + k0 + c0);
        bf16x8 b1 = *(const bf16x8*)(Bt + (size_t)(n0 + r1) * K + k0 + c0);
        __syncthreads();
        *(bf16x8*)(As + r0 * 32 + c0) = a0;
        *(bf16x8*)(As + r1 * 32 + c0) = a1;
        *(bf16x8*)(Bs + r0 * 32 + c0) = b0;
        *(bf16x8*)(Bs + r1 * 32 + c0) = b1;
        __syncthreads();
        bf16x8 af[4], bfr[4];
#pragma unroll
        for (int t = 0; t < 4; t++) {
            af[t] = *(const bf16x8*)(As + (wm + t * 16 + l16) * 32 + quad * 8);
            bfr[t] = *(const bf16x8*)(Bs + (wn + t * 16 + l16) * 32 + quad * 8);
        }
#pragma unroll
        for (int mt = 0; mt < 4; mt++)
#pragma unroll
            for (int nt = 0; nt < 4; nt++)
                acc[mt][nt] = mfma16(af[mt], bfr[nt], acc[mt][nt]);
    }

#pragma unroll
    for (int mt = 0; mt < 4; mt++) {
#pragma unroll
        for (int nt = 0; nt < 4; nt++) {
#pragma unroll
            for (int r = 0; r < 4; r++) {
                int gm = m0 + wm + mt * 16 + quad * 4 + r;
                int gn = n0 + wn + nt * 16 + l16;
                float v = acc[mt][nt][r];
                if (EPI == 1) {
                    Cout[(size_t)gm * N + gn] = v;
                } else {
                    int b = gm >> 11, s = gm & 2047;
                    int h = gn >> 6, dk = gn & 63;
                    short bv = bf16b(v);
                    if (blockIdx.z == 0)
                        Cq[(((size_t)(b * HH + h)) * SS + s) * DKK + dk] = bv;
                    else if (blockIdx.z == 1)
                        Ck[(((size_t)(b * HH + h)) * SS + s) * DKK + dk] = bv;
                    else
                        Cvt[(((size_t)(b * HH + h)) * DKK + dk) * SS + s] = bv;
                }
            }
        }
    }
}

// ---------------- flash attention ----------------
// grid (S/64, B*H), block 256 (4 waves; wave handles 16 q-rows)
__global__ __launch_bounds__(256) void attn(
    const short* __restrict__ Q, const short* __restrict__ Kmat,
    const short* __restrict__ Vt, const float* __restrict__ btab,
    short* __restrict__ O) {
    __shared__ float bias_s[4096];
    __shared__ short P_s[4][16 * 32];
    int tid = threadIdx.x;
    int wave = tid >> 6, lane = tid & 63;
    int quad = lane >> 4, l16 = lane & 15;
    int bh = blockIdx.y;
    int h = bh & 15, b = bh >> 4;
    int q0 = blockIdx.x * 64 + wave * 16;

    const float* bt = btab + h * 4095;
    for (int i = tid; i < 4095; i += 256) bias_s[i] = bt[i];
    __syncthreads();

    const short* Qb = Q + (size_t)bh * SS * DKK;
    const short* Kb = Kmat + (size_t)bh * SS * DKK;
    const short* Vb = Vt + (size_t)bh * DKK * SS;

    bf16x8 qf0 = *(const bf16x8*)(Qb + (q0 + l16) * DKK + quad * 8);
    bf16x8 qf1 = *(const bf16x8*)(Qb + (q0 + l16) * DKK + 32 + quad * 8);

    f32x4 o[4];
#pragma unroll
    for (int i = 0; i < 4; i++) o[i] = (f32x4){0.f, 0.f, 0.f, 0.f};
    float m_i[4], l_i[4];
#pragma unroll
    for (int r = 0; r < 4; r++) { m_i[r] = -1e30f; l_i[r] = 0.f; }

    short* Pw = &P_s[wave][0];
    int qrow_base = q0 + quad * 4;

    for (int kc = 0; kc < SS; kc += 32) {
        bf16x8 kf00 = *(const bf16x8*)(Kb + (kc + l16) * DKK + quad * 8);
        bf16x8 kf01 = *(const bf16x8*)(Kb + (kc + l16) * DKK + 32 + quad * 8);
        bf16x8 kf10 = *(const bf16x8*)(Kb + (kc + 16 + l16) * DKK + quad * 8);
        bf16x8 kf11 = *(const bf16x8*)(Kb + (kc + 16 + l16) * DKK + 32 + quad * 8);
        f32x4 s0 = (f32x4){0.f, 0.f, 0.f, 0.f};
        f32x4 s1 = (f32x4){0.f, 0.f, 0.f, 0.f};
        s0 = mfma16(qf0, kf00, s0);
        s0 = mfma16(qf1, kf01, s0);
        s1 = mfma16(qf0, kf10, s1);
        s1 = mfma16(qf1, kf11, s1);

        float sv0[4], sv1[4];
#pragma unroll
        for (int r = 0; r < 4; r++) {
            int base = kc + 2047 - (qrow_base + r);
            sv0[r] = s0[r] + bias_s[base + l16];
            sv1[r] = s1[r] + bias_s[base + l16 + 16];
        }
        float mx[4];
#pragma unroll
        for (int r = 0; r < 4; r++) mx[r] = fmaxf(sv0[r], sv1[r]);
#pragma unroll
        for (int off = 1; off < 16; off <<= 1)
#pragma unroll
            for (int r = 0; r < 4; r++)
                mx[r] = fmaxf(mx[r], __shfl_xor(mx[r], off));

        float alpha[4];
#pragma unroll
        for (int r = 0; r < 4; r++) {
            float mn = fmaxf(m_i[r], mx[r]);
            alpha[r] = __expf(m_i[r] - mn);
            m_i[r] = mn;
        }
        float p0[4], p1[4], sum[4];
#pragma unroll
        for (int r = 0; r < 4; r++) {
            p0[r] = __expf(sv0[r] - m_i[r]);
            p1[r] = __expf(sv1[r] - m_i[r]);
            sum[r] = p0[r] + p1[r];
        }
#pragma unroll
        for (int off = 1; off < 16; off <<= 1)
#pragma unroll
            for (int r = 0; r < 4; r++)
                sum[r] += __shfl_xor(sum[r], off);
#pragma unroll
        for (int r = 0; r < 4; r++) l_i[r] = l_i[r] * alpha[r] + sum[r];
#pragma unroll
        for (int nt = 0; nt < 4; nt++)
#pragma unroll
            for (int r = 0; r < 4; r++) o[nt][r] *= alpha[r];

#pragma unroll
        for (int r = 0; r < 4; r++) {
            Pw[(quad * 4 + r) * 32 + l16] = bf16b(p0[r]);
            Pw[(quad * 4 + r) * 32 + l16 + 16] = bf16b(p1[r]);
        }
        __syncthreads(); // cross-lane LDS visibility (each wave owns its P region)
        bf16x8 pf = *(const bf16x8*)(Pw + l16 * 32 + quad * 8);
#pragma unroll
        for (int nt = 0; nt < 4; nt++) {
            bf16x8 vf = *(const bf16x8*)(Vb + (nt * 16 + l16) * SS + kc + quad * 8);
            o[nt] = mfma16(pf, vf, o[nt]);
        }
    }

    float inv[4];
#pragma unroll
    for (int r = 0; r < 4; r++) inv[r] = 1.f / l_i[r];
#pragma unroll
    for (int nt = 0; nt < 4; nt++)
#pragma unroll
        for (int r = 0; r < 4; r++) {
            int qrow = qrow_base + r;
            int dk = nt * 16 + l16;
            O[((size_t)(b * SS + qrow)) * (HH * DKK) + h * DKK + dk] =
                bf16b(o[nt][r] * inv[r]);
        }
}

extern "C" void kernel_launch(void* const* d_in, const int* in_sizes, int n_in,
                              void* d_out, int out_size, void* d_ws, size_t ws_size,
                              hipStream_t stream) {
    const float* hs = (const float*)d_in[0];
    const float* Wq = (const float*)d_in[1];
    const float* Wk = (const float*)d_in[2];
    const float* Wv = (const float*)d_in[3];
    const float* Wo = (const float*)d_in[4];
    const float* rb = (const float*)d_in[5];
    float* out = (float*)d_out;

    char* ws = (char*)d_ws;
    size_t off = 0;
    auto alloc = [&](size_t bytes) -> void* {
        void* p = (void*)(ws + off);
        off += (bytes + 255) & ~(size_t)255;
        return p;
    };
    const size_t M = (size_t)BB * SS; // 4096
    short* hsb = (short*)alloc(M * DD * 2);
    short* WqT = (short*)alloc((size_t)DD * DD * 2);
    short* WkT = (short*)alloc((size_t)DD * DD * 2);
    short* WvT = (short*)alloc((size_t)DD * DD * 2);
    short* WoT = (short*)alloc((size_t)DD * DD * 2);
    short* Qb  = (short*)alloc(M * DD * 2);
    short* Kb  = (short*)alloc(M * DD * 2);
    short* VTb = (short*)alloc(M * DD * 2);
    short* Ab  = (short*)alloc(M * DD * 2);
    float* btab = (float*)alloc((size_t)HH * 4095 * 4);

    int nHS = (int)(M * DD);
    cvt_bf16<<<nHS / 1024, 256, 0, stream>>>(hs, hsb, nHS);
    transpose_w<<<dim3(32, 32, 4), 256, 0, stream>>>(Wq, Wk, Wv, Wo, WqT, WkT, WvT, WoT);
    build_bias<<<(HH * 4095 + 255) / 256, 256, 0, stream>>>(rb, btab);
    gemm_bt<0><<<dim3(8, 32, 3), 256, 0, stream>>>(hsb, WqT, WkT, WvT, Qb, Kb, VTb, nullptr);
    attn<<<dim3(32, 32), 256, 0, stream>>>(Qb, Kb, VTb, btab, Ab);
    gemm_bt<1><<<dim3(8, 32, 1), 256, 0, stream>>>(Ab, WoT, nullptr, nullptr,
                                                   nullptr, nullptr, nullptr, out);
}